// Round 1
// baseline (119.623 us; speedup 1.0000x reference)
//
#include <hip/hip_runtime.h>

typedef unsigned int u32;
typedef unsigned short u16;
typedef __attribute__((ext_vector_type(8))) short short8;
typedef __attribute__((ext_vector_type(4))) float f32x4;

#define LSEQ 2048
#define DM 1024
#define HWIN 128

__device__ __forceinline__ u16 f2bf(float f) {
  union { float f; u32 u; } v; v.f = f;
  u32 r = v.u + 0x7FFFu + ((v.u >> 16) & 1u);
  return (u16)(r >> 16);
}
__device__ __forceinline__ u32 packbf(float lo, float hi) {
  return (u32)f2bf(lo) | ((u32)f2bf(hi) << 16);
}

typedef __attribute__((address_space(3))) u32 lds_u32;
typedef __attribute__((address_space(1))) const u32 glob_u32;
__device__ __forceinline__ void g2lds16(const void* g, void* l) {
  __builtin_amdgcn_global_load_lds((glob_u32*)g, (lds_u32*)l, 16, 0, 0);
}

// ---------------- LayerNorm: fp32 in -> bf16 xn ----------------
__global__ __launch_bounds__(256) void ln_kernel(const float* __restrict__ x,
                                                 const float* __restrict__ gamma,
                                                 const float* __restrict__ beta,
                                                 u16* __restrict__ xn) {
  int r = blockIdx.x;
  int t = threadIdx.x;
  const float4* xr = (const float4*)(x + (size_t)r * DM);
  float4 v = xr[t];
  float s = v.x + v.y + v.z + v.w;
  float s2 = v.x * v.x + v.y * v.y + v.z * v.z + v.w * v.w;
#pragma unroll
  for (int o = 32; o; o >>= 1) { s += __shfl_xor(s, o); s2 += __shfl_xor(s2, o); }
  __shared__ float ws1[4], ws2[4];
  if ((t & 63) == 0) { ws1[t >> 6] = s; ws2[t >> 6] = s2; }
  __syncthreads();
  s = ws1[0] + ws1[1] + ws1[2] + ws1[3];
  s2 = ws2[0] + ws2[1] + ws2[2] + ws2[3];
  float mu = s * (1.0f / DM);
  float var = s2 * (1.0f / DM) - mu * mu;
  float rs = rsqrtf(var + 1e-5f);
  float4 g = ((const float4*)gamma)[t];
  float4 b = ((const float4*)beta)[t];
  u32 lo = packbf((v.x - mu) * rs * g.x + b.x, (v.y - mu) * rs * g.y + b.y);
  u32 hi = packbf((v.z - mu) * rs * g.z + b.z, (v.w - mu) * rs * g.w + b.w);
  u32* dst = (u32*)(xn + (size_t)r * DM) + t * 2;
  dst[0] = lo; dst[1] = hi;
}

// ---------------- fp32 -> bf16 cast (weights) ----------------
__global__ __launch_bounds__(256) void cvt_kernel(const float* __restrict__ in,
                                                  u16* __restrict__ out, int n4) {
  int i = blockIdx.x * 256 + threadIdx.x;
  if (i >= n4) return;
  float4 v = ((const float4*)in)[i];
  u32* dst = (u32*)out + i * 2;
  dst[0] = packbf(v.x, v.y);
  dst[1] = packbf(v.z, v.w);
}

// ---------------- GEMM C = A @ B^T, 128x128 tile, BK=32 ----------------
// MODE 0: qkv projection epilogue (bf16; cols<2048 -> qk buffer, cols>=2048 -> v_t transposed)
// MODE 1: out projection epilogue (fp32 out = residual + acc)
template <int MODE>
__global__ __launch_bounds__(256) void gemm_bt(const u16* __restrict__ Ag,
                                               const u16* __restrict__ Bg,
                                               int K, int NB,
                                               u16* __restrict__ qk_out,
                                               u16* __restrict__ vt_out,
                                               const float* __restrict__ resid,
                                               float* __restrict__ out) {
  __shared__ __align__(16) u16 As[128 * 32];
  __shared__ __align__(16) u16 Bs[128 * 32];
  int tid = threadIdx.x;
  int w = tid >> 6, l = tid & 63;
  int lg = l >> 4, li = l & 15;
  int bm = blockIdx.x / NB, bn = blockIdx.x % NB;
  int wr = w >> 1, wc = w & 1;
  f32x4 acc[4][4];
#pragma unroll
  for (int m = 0; m < 4; ++m)
#pragma unroll
    for (int n = 0; n < 4; ++n) acc[m][n] = (f32x4){0.f, 0.f, 0.f, 0.f};

  const u16* aS = Ag + (size_t)(bm * 128 + w * 32 + (l >> 2)) * K + (l & 3) * 8;
  const u16* bS = Bg + (size_t)(bn * 128 + w * 32 + (l >> 2)) * K + (l & 3) * 8;
  u16* aL = As + w * 1024;
  u16* bL = Bs + w * 1024;
  const size_t r16 = (size_t)16 * K;

  for (int k0 = 0; k0 < K; k0 += 32) {
    __syncthreads();  // previous compute done before overwrite
    g2lds16(aS + k0, aL);
    g2lds16(aS + k0 + r16, aL + 512);
    g2lds16(bS + k0, bL);
    g2lds16(bS + k0 + r16, bL + 512);
    __syncthreads();  // staging visible (compiler drains vmcnt before barrier)
    short8 af[4], bf[4];
#pragma unroll
    for (int m = 0; m < 4; ++m)
      af[m] = *(const short8*)&As[(wr * 64 + m * 16 + li) * 32 + lg * 8];
#pragma unroll
    for (int n = 0; n < 4; ++n)
      bf[n] = *(const short8*)&Bs[(wc * 64 + n * 16 + li) * 32 + lg * 8];
#pragma unroll
    for (int m = 0; m < 4; ++m)
#pragma unroll
      for (int n = 0; n < 4; ++n)
        acc[m][n] = __builtin_amdgcn_mfma_f32_16x16x32_bf16(af[m], bf[n], acc[m][n], 0, 0, 0);
  }

  int colbase = bn * 128 + wc * 64;
  int rowbase = bm * 128 + wr * 64;
#pragma unroll
  for (int m = 0; m < 4; ++m) {
    int row = rowbase + m * 16 + lg * 4;  // + r ; C layout: col=l&15, row=(l>>4)*4+reg
#pragma unroll
    for (int n = 0; n < 4; ++n) {
      int col = colbase + n * 16 + li;
      if (MODE == 0) {
        if (colbase < 2048) {
#pragma unroll
          for (int r = 0; r < 4; ++r)
            qk_out[(size_t)(row + r) * 2048 + col] = f2bf(acc[m][n][r]);
        } else {
          // V written transposed: vt[b][h*64+hd][key]; regs r are consecutive keys
          int b = row >> 11;
          int hdcol = col - 2048;
          size_t idx = ((size_t)b * 1024 + hdcol) * 2048 + (row & 2047);
          u32* d = (u32*)&vt_out[idx];
          d[0] = packbf(acc[m][n][0], acc[m][n][1]);
          d[1] = packbf(acc[m][n][2], acc[m][n][3]);
        }
      } else {
#pragma unroll
        for (int r = 0; r < 4; ++r) {
          size_t idx = (size_t)(row + r) * 1024 + col;
          out[idx] = resid[idx] + acc[m][n][r];
        }
      }
    }
  }
}

// ---------------- banded attention, swapped S^T = mfma(K, Q) ----------------
// grid = (B*H)*32 blocks; 4 waves/block, 16 queries/wave; no LDS (K/V are L2-resident)
__global__ __launch_bounds__(256) void attn_kernel(const u16* __restrict__ qk,
                                                   const u16* __restrict__ vt,
                                                   u16* __restrict__ ato) {
  int blk = blockIdx.x;
  int bh = blk >> 5;
  int qblk = blk & 31;
  int b = bh >> 4, h = bh & 15;
  int tid = threadIdx.x;
  int w = tid >> 6, l = tid & 63;
  int lg = l >> 4, li = l & 15;
  int qw = qblk * 64 + w * 16;
  int q = qw + li;  // this lane's query (S^T col = l&15)

  // Q fragment (B operand): lane holds Q[q=li][hd=(l>>4)*8+j], hd steps {0,32}
  const u16* qbase = qk + (size_t)(b * 2048 + q) * 2048 + h * 64 + lg * 8;
  short8 qf0 = *(const short8*)qbase;
  short8 qf1 = *(const short8*)(qbase + 32);

  const u16* kbase = qk + (size_t)b * 2048 * 2048 + 1024 + h * 64 + lg * 8;
  const u16* vbase = vt + (size_t)(bh * 64 + li) * 2048;

  f32x4 o0 = {0,0,0,0}, o1 = {0,0,0,0}, o2 = {0,0,0,0}, o3 = {0,0,0,0};
  float m = -1e30f, lsum = 0.f;

  int lo = qw - HWIN; if (lo < 0) lo = 0;
  int hi = qw + 15 + HWIN; if (hi > LSEQ - 1) hi = LSEQ - 1;
  const float SC = 0.125f * 1.44269504088896f;  // 1/sqrt(64) * log2(e)

  for (int kb = lo & ~31; kb <= hi; kb += 32) {
    // ---- S^T tiles (16 keys x 16 queries each) ----
    const u16* kp0 = kbase + (size_t)(kb + li) * 2048;
    const u16* kp1 = kbase + (size_t)(kb + 16 + li) * 2048;
    short8 k00 = *(const short8*)kp0;
    short8 k01 = *(const short8*)(kp0 + 32);
    short8 k10 = *(const short8*)kp1;
    short8 k11 = *(const short8*)(kp1 + 32);
    f32x4 c0 = {0,0,0,0}, c1 = {0,0,0,0};
    c0 = __builtin_amdgcn_mfma_f32_16x16x32_bf16(k00, qf0, c0, 0, 0, 0);
    c0 = __builtin_amdgcn_mfma_f32_16x16x32_bf16(k01, qf1, c0, 0, 0, 0);
    c1 = __builtin_amdgcn_mfma_f32_16x16x32_bf16(k10, qf0, c1, 0, 0, 0);
    c1 = __builtin_amdgcn_mfma_f32_16x16x32_bf16(k11, qf1, c1, 0, 0, 0);

    // ---- band mask + online softmax (each lane = one query) ----
    float t[8];
#pragma unroll
    for (int r = 0; r < 4; ++r) {
      int key0 = kb + lg * 4 + r;
      int key1 = key0 + 16;
      int d0 = key0 - q, d1 = key1 - q;
      t[r]     = (d0 >= -HWIN && d0 <= HWIN && key0 < LSEQ) ? c0[r] * SC : -__builtin_inff();
      t[r + 4] = (d1 >= -HWIN && d1 <= HWIN && key1 < LSEQ) ? c1[r] * SC : -__builtin_inff();
    }
    float mc = t[0];
#pragma unroll
    for (int i = 1; i < 8; ++i) mc = fmaxf(mc, t[i]);
    mc = fmaxf(mc, __shfl_xor(mc, 16));
    mc = fmaxf(mc, __shfl_xor(mc, 32));
    float mn = fmaxf(m, mc);
    float corr = __builtin_amdgcn_exp2f(m - mn);
    float p[8]; float ssum = 0.f;
#pragma unroll
    for (int i = 0; i < 8; ++i) { p[i] = __builtin_amdgcn_exp2f(t[i] - mn); ssum += p[i]; }
    ssum += __shfl_xor(ssum, 16);
    ssum += __shfl_xor(ssum, 32);
    lsum = lsum * corr + ssum;
    m = mn;
    o0 *= corr; o1 *= corr; o2 *= corr; o3 *= corr;

    // ---- P: C layout (keys 4*lg+r) -> B-frag layout (keys 8*lg+j), 8 shuffles ----
    u32 a0 = packbf(p[0], p[1]);
    u32 a1 = packbf(p[2], p[3]);
    u32 b0 = packbf(p[4], p[5]);
    u32 b1 = packbf(p[6], p[7]);
    int sg0 = (((2 * lg) & 3) << 4) + li;
    int sg1 = (((2 * lg + 1) & 3) << 4) + li;
    u32 w0 = (u32)__shfl((int)a0, sg0), w1 = (u32)__shfl((int)a1, sg0);
    u32 w2 = (u32)__shfl((int)a0, sg1), w3 = (u32)__shfl((int)a1, sg1);
    u32 x0 = (u32)__shfl((int)b0, sg0), x1 = (u32)__shfl((int)b1, sg0);
    u32 x2 = (u32)__shfl((int)b0, sg1), x3 = (u32)__shfl((int)b1, sg1);
    bool lohalf = lg < 2;
    union { u32 u[4]; short8 s; } pf;
    pf.u[0] = lohalf ? w0 : x0;
    pf.u[1] = lohalf ? w1 : x1;
    pf.u[2] = lohalf ? w2 : x2;
    pf.u[3] = lohalf ? w3 : x3;

    // ---- PV: out^T[hd][q] += V^T[hd][k] * P^T[k][q]; V^T rows contiguous in vt ----
    const u16* vp = vbase + kb + lg * 8;
    short8 v0 = *(const short8*)(vp);
    short8 v1 = *(const short8*)(vp + (size_t)16 * 2048);
    short8 v2 = *(const short8*)(vp + (size_t)32 * 2048);
    short8 v3 = *(const short8*)(vp + (size_t)48 * 2048);
    o0 = __builtin_amdgcn_mfma_f32_16x16x32_bf16(v0, pf.s, o0, 0, 0, 0);
    o1 = __builtin_amdgcn_mfma_f32_16x16x32_bf16(v1, pf.s, o1, 0, 0, 0);
    o2 = __builtin_amdgcn_mfma_f32_16x16x32_bf16(v2, pf.s, o2, 0, 0, 0);
    o3 = __builtin_amdgcn_mfma_f32_16x16x32_bf16(v3, pf.s, o3, 0, 0, 0);
  }

  float inv = 1.0f / lsum;
  u16* orow = ato + (size_t)(b * 2048 + q) * 1024 + h * 64 + lg * 4;
  *(u32*)(orow +  0) = packbf(o0[0] * inv, o0[1] * inv);
  *(u32*)(orow +  2) = packbf(o0[2] * inv, o0[3] * inv);
  *(u32*)(orow + 16) = packbf(o1[0] * inv, o1[1] * inv);
  *(u32*)(orow + 18) = packbf(o1[2] * inv, o1[3] * inv);
  *(u32*)(orow + 32) = packbf(o2[0] * inv, o2[1] * inv);
  *(u32*)(orow + 34) = packbf(o2[2] * inv, o2[3] * inv);
  *(u32*)(orow + 48) = packbf(o3[0] * inv, o3[1] * inv);
  *(u32*)(orow + 50) = packbf(o3[2] * inv, o3[3] * inv);
}

extern "C" void kernel_launch(void* const* d_in, const int* in_sizes, int n_in,
                              void* d_out, int out_size, void* d_ws, size_t ws_size,
                              hipStream_t stream) {
  const float* x     = (const float*)d_in[0];
  const float* w_qkv = (const float*)d_in[1];
  const float* w_out = (const float*)d_in[2];
  const float* gamma = (const float*)d_in[3];
  const float* beta  = (const float*)d_in[4];
  float* out = (float*)d_out;
  char* ws = (char*)d_ws;

  // workspace layout (48 MB total)
  u16* xn  = (u16*)(ws);              //  8 MB  [4096][1024] bf16
  u16* wq  = (u16*)(ws + 8388608);    //  6 MB  [3072][1024] bf16
  u16* wo  = (u16*)(ws + 14680064);   //  2 MB  [1024][1024] bf16
  u16* qkb = (u16*)(ws + 16777216);   // 16 MB  [4096][2048] bf16 (Q|K)
  u16* vt  = (u16*)(ws + 33554432);   //  8 MB  [2][1024][2048] bf16 (V^T)
  u16* ao  = (u16*)(ws + 41943040);   //  8 MB  [4096][1024] bf16 attn out

  ln_kernel<<<4096, 256, 0, stream>>>(x, gamma, beta, xn);
  cvt_kernel<<<3072, 256, 0, stream>>>(w_qkv, wq, 786432);
  cvt_kernel<<<1024, 256, 0, stream>>>(w_out, wo, 262144);
  gemm_bt<0><<<32 * 24, 256, 0, stream>>>(xn, wq, 1024, 24, qkb, vt, nullptr, nullptr);
  attn_kernel<<<32 * 32, 256, 0, stream>>>(qkb, vt, ao);
  gemm_bt<1><<<32 * 8, 256, 0, stream>>>(ao, wo, 1024, 8, nullptr, nullptr, x, out);
}

// Round 2
// 105.791 us; speedup vs baseline: 1.1307x; 1.1307x over previous
//
#include <hip/hip_runtime.h>

typedef unsigned int u32;
typedef unsigned short u16;
typedef __attribute__((ext_vector_type(8))) short short8;
typedef __attribute__((ext_vector_type(4))) float f32x4;

#define LSEQ 2048
#define DM 1024
#define HWIN 128

__device__ __forceinline__ u16 f2bf(float f) {
  union { float f; u32 u; } v; v.f = f;
  u32 r = v.u + 0x7FFFu + ((v.u >> 16) & 1u);
  return (u16)(r >> 16);
}
__device__ __forceinline__ u32 packbf(float lo, float hi) {
  return (u32)f2bf(lo) | ((u32)f2bf(hi) << 16);
}

typedef __attribute__((address_space(3))) u32 lds_u32;
typedef __attribute__((address_space(1))) const u32 glob_u32;
__device__ __forceinline__ void g2lds16(const void* g, void* l) {
  __builtin_amdgcn_global_load_lds((glob_u32*)g, (lds_u32*)l, 16, 0, 0);
}

// ---------------- LayerNorm: fp32 in -> bf16 xn ----------------
__global__ __launch_bounds__(256) void ln_kernel(const float* __restrict__ x,
                                                 const float* __restrict__ gamma,
                                                 const float* __restrict__ beta,
                                                 u16* __restrict__ xn) {
  int r = blockIdx.x;
  int t = threadIdx.x;
  const float4* xr = (const float4*)(x + (size_t)r * DM);
  float4 v = xr[t];
  float s = v.x + v.y + v.z + v.w;
  float s2 = v.x * v.x + v.y * v.y + v.z * v.z + v.w * v.w;
#pragma unroll
  for (int o = 32; o; o >>= 1) { s += __shfl_xor(s, o); s2 += __shfl_xor(s2, o); }
  __shared__ float ws1[4], ws2[4];
  if ((t & 63) == 0) { ws1[t >> 6] = s; ws2[t >> 6] = s2; }
  __syncthreads();
  s = ws1[0] + ws1[1] + ws1[2] + ws1[3];
  s2 = ws2[0] + ws2[1] + ws2[2] + ws2[3];
  float mu = s * (1.0f / DM);
  float var = s2 * (1.0f / DM) - mu * mu;
  float rs = rsqrtf(var + 1e-5f);
  float4 g = ((const float4*)gamma)[t];
  float4 b = ((const float4*)beta)[t];
  u32 lo = packbf((v.x - mu) * rs * g.x + b.x, (v.y - mu) * rs * g.y + b.y);
  u32 hi = packbf((v.z - mu) * rs * g.z + b.z, (v.w - mu) * rs * g.w + b.w);
  u32* dst = (u32*)(xn + (size_t)r * DM) + t * 2;
  dst[0] = lo; dst[1] = hi;
}

// ---------------- fp32 -> bf16 cast (both weight matrices, one launch) ----------------
__global__ __launch_bounds__(256) void cvt2_kernel(const float* __restrict__ a,
                                                   const float* __restrict__ b,
                                                   u16* __restrict__ oa,
                                                   u16* __restrict__ ob) {
  int blk = blockIdx.x;
  const float* in; u16* out; int i;
  if (blk < 3072) { in = a; out = oa; i = blk * 256 + threadIdx.x; }
  else            { in = b; out = ob; i = (blk - 3072) * 256 + threadIdx.x; }
  float4 v = ((const float4*)in)[i];
  u32* dst = (u32*)out + i * 2;
  dst[0] = packbf(v.x, v.y);
  dst[1] = packbf(v.z, v.w);
}

// ---- stage one 128x64 bf16 tile (rows gr0.., cols k0..k0+63) into lbuf ----
// LDS dest is linear (global_load_lds writes base + lane*16); the XOR swizzle
// is applied to the GLOBAL source column so that physical chunk (row, cp)
// holds logical chunk (row, cp ^ (row&7)). Reader applies same involution.
__device__ __forceinline__ void stage_tile(const u16* __restrict__ G, int gr0, int K,
                                           int k0, u16* lbuf, int tid, int w) {
#pragma unroll
  for (int j = 0; j < 4; ++j) {
    int rp = j * 32 + (tid >> 3);
    int ce = ((tid & 7) ^ (rp & 7)) * 8;
    g2lds16(G + (size_t)(gr0 + rp) * K + k0 + ce, lbuf + j * 2048 + w * 512);
  }
}

// ---------------- GEMM C = A @ B^T, 128x128 tile, BK=64, 2-phase dbuf ----------------
// MODE 0: qkv projection epilogue; MODE 1: out projection (fp32 out = resid + acc)
template <int MODE>
__global__ __launch_bounds__(256) void gemm_bt(const u16* __restrict__ Ag,
                                               const u16* __restrict__ Bg,
                                               int K, int NB,
                                               u16* __restrict__ qk_out,
                                               u16* __restrict__ vt_out,
                                               const float* __restrict__ resid,
                                               float* __restrict__ out) {
  __shared__ __align__(16) u16 sm[32768];  // 2 bufs x (A 128x64 + B 128x64) = 64 KB
  int tid = threadIdx.x;
  int w = tid >> 6, l = tid & 63;
  int lg = l >> 4, li = l & 15;
  int bm = blockIdx.x / NB, bn = blockIdx.x % NB;
  int wr = w >> 1, wc = w & 1;
  f32x4 acc[4][4];
#pragma unroll
  for (int m = 0; m < 4; ++m)
#pragma unroll
    for (int n = 0; n < 4; ++n) acc[m][n] = (f32x4){0.f, 0.f, 0.f, 0.f};

  int nt = K >> 6;
  stage_tile(Ag, bm * 128, K, 0, sm, tid, w);
  stage_tile(Bg, bn * 128, K, 0, sm + 8192, tid, w);
  asm volatile("s_waitcnt vmcnt(0)" ::: "memory");
  __builtin_amdgcn_s_barrier();
  asm volatile("" ::: "memory");

  int cur = 0;
  for (int t = 0; t < nt; ++t) {
    if (t + 1 < nt) {  // issue next-tile loads BEFORE compute (latency hides under MFMA)
      stage_tile(Ag, bm * 128, K, (t + 1) << 6, sm + (cur ^ 1) * 16384, tid, w);
      stage_tile(Bg, bn * 128, K, (t + 1) << 6, sm + (cur ^ 1) * 16384 + 8192, tid, w);
    }
    const u16* Ab = sm + cur * 16384;
    const u16* Bb = Ab + 8192;
#pragma unroll
    for (int ks = 0; ks < 2; ++ks) {
      short8 af[4], bf4[4];
#pragma unroll
      for (int m = 0; m < 4; ++m)
        af[m] = *(const short8*)&Ab[(wr * 64 + m * 16 + li) * 64 + (((lg + ks * 4) ^ (li & 7)) * 8)];
#pragma unroll
      for (int n = 0; n < 4; ++n)
        bf4[n] = *(const short8*)&Bb[(wc * 64 + n * 16 + li) * 64 + (((lg + ks * 4) ^ (li & 7)) * 8)];
#pragma unroll
      for (int m = 0; m < 4; ++m)
#pragma unroll
        for (int n = 0; n < 4; ++n)
          acc[m][n] = __builtin_amdgcn_mfma_f32_16x16x32_bf16(af[m], bf4[n], acc[m][n], 0, 0, 0);
    }
    asm volatile("s_waitcnt vmcnt(0)" ::: "memory");
    __builtin_amdgcn_s_barrier();
    asm volatile("" ::: "memory");
    cur ^= 1;
  }

  int colbase = bn * 128 + wc * 64;
  int rowbase = bm * 128 + wr * 64;
#pragma unroll
  for (int m = 0; m < 4; ++m) {
    int row = rowbase + m * 16 + lg * 4;  // C layout: col=l&15, row=(l>>4)*4+reg
#pragma unroll
    for (int n = 0; n < 4; ++n) {
      int col = colbase + n * 16 + li;
      if (MODE == 0) {
        if (colbase < 2048) {
#pragma unroll
          for (int r = 0; r < 4; ++r)
            qk_out[(size_t)(row + r) * 2048 + col] = f2bf(acc[m][n][r]);
        } else {
          // V transposed: vt[b][h*64+hd][key]; regs r are consecutive keys
          int b = row >> 11;
          int hdcol = col - 2048;
          size_t idx = ((size_t)b * 1024 + hdcol) * 2048 + (row & 2047);
          u32* d = (u32*)&vt_out[idx];
          d[0] = packbf(acc[m][n][0], acc[m][n][1]);
          d[1] = packbf(acc[m][n][2], acc[m][n][3]);
        }
      } else {
#pragma unroll
        for (int r = 0; r < 4; ++r) {
          size_t idx = (size_t)(row + r) * 1024 + col;
          out[idx] = resid[idx] + acc[m][n][r];
        }
      }
    }
  }
}

// ---------------- banded attention, swapped S^T = mfma(K, Q) ----------------
__global__ __launch_bounds__(256) void attn_kernel(const u16* __restrict__ qk,
                                                   const u16* __restrict__ vt,
                                                   u16* __restrict__ ato) {
  int blk = blockIdx.x;
  int bh = blk >> 5;
  int qblk = blk & 31;
  int b = bh >> 4, h = bh & 15;
  int tid = threadIdx.x;
  int w = tid >> 6, l = tid & 63;
  int lg = l >> 4, li = l & 15;
  int qw = qblk * 64 + w * 16;
  int q = qw + li;  // this lane's query (S^T col = l&15)

  const u16* qbase = qk + (size_t)(b * 2048 + q) * 2048 + h * 64 + lg * 8;
  short8 qf0 = *(const short8*)qbase;
  short8 qf1 = *(const short8*)(qbase + 32);

  const u16* kbase = qk + (size_t)b * 2048 * 2048 + 1024 + h * 64 + lg * 8;
  const u16* vbase = vt + (size_t)(bh * 64 + li) * 2048;

  f32x4 o0 = {0,0,0,0}, o1 = {0,0,0,0}, o2 = {0,0,0,0}, o3 = {0,0,0,0};
  float m = -1e30f, lsum = 0.f;

  int lo = qw - HWIN; if (lo < 0) lo = 0;
  int hi = qw + 15 + HWIN; if (hi > LSEQ - 1) hi = LSEQ - 1;
  const float SC = 0.125f * 1.44269504088896f;  // 1/sqrt(64) * log2(e)

  for (int kb = lo & ~31; kb <= hi; kb += 32) {
    const u16* kp0 = kbase + (size_t)(kb + li) * 2048;
    const u16* kp1 = kbase + (size_t)(kb + 16 + li) * 2048;
    short8 k00 = *(const short8*)kp0;
    short8 k01 = *(const short8*)(kp0 + 32);
    short8 k10 = *(const short8*)kp1;
    short8 k11 = *(const short8*)(kp1 + 32);
    f32x4 c0 = {0,0,0,0}, c1 = {0,0,0,0};
    c0 = __builtin_amdgcn_mfma_f32_16x16x32_bf16(k00, qf0, c0, 0, 0, 0);
    c0 = __builtin_amdgcn_mfma_f32_16x16x32_bf16(k01, qf1, c0, 0, 0, 0);
    c1 = __builtin_amdgcn_mfma_f32_16x16x32_bf16(k10, qf0, c1, 0, 0, 0);
    c1 = __builtin_amdgcn_mfma_f32_16x16x32_bf16(k11, qf1, c1, 0, 0, 0);

    // ---- band mask (skipped on wave-uniform interior chunks) ----
    float t[8];
    bool interior = (kb >= qw + 15 - HWIN) && (kb + 31 <= qw + HWIN) && (kb + 31 < LSEQ);
    if (interior) {
#pragma unroll
      for (int r = 0; r < 4; ++r) { t[r] = c0[r] * SC; t[r + 4] = c1[r] * SC; }
    } else {
#pragma unroll
      for (int r = 0; r < 4; ++r) {
        int key0 = kb + lg * 4 + r;
        int key1 = key0 + 16;
        int d0 = key0 - q, d1 = key1 - q;
        t[r]     = (d0 >= -HWIN && d0 <= HWIN && key0 < LSEQ) ? c0[r] * SC : -__builtin_inff();
        t[r + 4] = (d1 >= -HWIN && d1 <= HWIN && key1 < LSEQ) ? c1[r] * SC : -__builtin_inff();
      }
    }
    float mc = t[0];
#pragma unroll
    for (int i = 1; i < 8; ++i) mc = fmaxf(mc, t[i]);
    mc = fmaxf(mc, __shfl_xor(mc, 16));
    mc = fmaxf(mc, __shfl_xor(mc, 32));

    float p[8]; float ssum;
    if (__all(mc <= m + 8.0f)) {
      // defer-max (T13): max didn't grow enough to matter; skip the O-rescale
      ssum = 0.f;
#pragma unroll
      for (int i = 0; i < 8; ++i) { p[i] = __builtin_amdgcn_exp2f(t[i] - m); ssum += p[i]; }
      ssum += __shfl_xor(ssum, 16);
      ssum += __shfl_xor(ssum, 32);
      lsum += ssum;
    } else {
      float mn = fmaxf(m, mc);
      float corr = __builtin_amdgcn_exp2f(m - mn);
      ssum = 0.f;
#pragma unroll
      for (int i = 0; i < 8; ++i) { p[i] = __builtin_amdgcn_exp2f(t[i] - mn); ssum += p[i]; }
      ssum += __shfl_xor(ssum, 16);
      ssum += __shfl_xor(ssum, 32);
      lsum = lsum * corr + ssum;
      m = mn;
      o0 *= corr; o1 *= corr; o2 *= corr; o3 *= corr;
    }

    // ---- P: C layout (keys 4*lg+r) -> B-frag layout (keys 8*lg+j), 8 shuffles ----
    u32 a0 = packbf(p[0], p[1]);
    u32 a1 = packbf(p[2], p[3]);
    u32 b0 = packbf(p[4], p[5]);
    u32 b1 = packbf(p[6], p[7]);
    int sg0 = (((2 * lg) & 3) << 4) + li;
    int sg1 = (((2 * lg + 1) & 3) << 4) + li;
    u32 w0 = (u32)__shfl((int)a0, sg0), w1 = (u32)__shfl((int)a1, sg0);
    u32 w2 = (u32)__shfl((int)a0, sg1), w3 = (u32)__shfl((int)a1, sg1);
    u32 x0 = (u32)__shfl((int)b0, sg0), x1 = (u32)__shfl((int)b1, sg0);
    u32 x2 = (u32)__shfl((int)b0, sg1), x3 = (u32)__shfl((int)b1, sg1);
    bool lohalf = lg < 2;
    union { u32 u[4]; short8 s; } pf;
    pf.u[0] = lohalf ? w0 : x0;
    pf.u[1] = lohalf ? w1 : x1;
    pf.u[2] = lohalf ? w2 : x2;
    pf.u[3] = lohalf ? w3 : x3;

    // ---- PV: out^T[hd][q] += V^T[hd][k] * P^T[k][q] ----
    const u16* vp = vbase + kb + lg * 8;
    short8 v0 = *(const short8*)(vp);
    short8 v1 = *(const short8*)(vp + (size_t)16 * 2048);
    short8 v2 = *(const short8*)(vp + (size_t)32 * 2048);
    short8 v3 = *(const short8*)(vp + (size_t)48 * 2048);
    o0 = __builtin_amdgcn_mfma_f32_16x16x32_bf16(v0, pf.s, o0, 0, 0, 0);
    o1 = __builtin_amdgcn_mfma_f32_16x16x32_bf16(v1, pf.s, o1, 0, 0, 0);
    o2 = __builtin_amdgcn_mfma_f32_16x16x32_bf16(v2, pf.s, o2, 0, 0, 0);
    o3 = __builtin_amdgcn_mfma_f32_16x16x32_bf16(v3, pf.s, o3, 0, 0, 0);
  }

  float inv = 1.0f / lsum;
  u16* orow = ato + (size_t)(b * 2048 + q) * 1024 + h * 64 + lg * 4;
  *(u32*)(orow +  0) = packbf(o0[0] * inv, o0[1] * inv);
  *(u32*)(orow +  2) = packbf(o0[2] * inv, o0[3] * inv);
  *(u32*)(orow + 16) = packbf(o1[0] * inv, o1[1] * inv);
  *(u32*)(orow + 18) = packbf(o1[2] * inv, o1[3] * inv);
  *(u32*)(orow + 32) = packbf(o2[0] * inv, o2[1] * inv);
  *(u32*)(orow + 34) = packbf(o2[2] * inv, o2[3] * inv);
  *(u32*)(orow + 48) = packbf(o3[0] * inv, o3[1] * inv);
  *(u32*)(orow + 50) = packbf(o3[2] * inv, o3[3] * inv);
}

extern "C" void kernel_launch(void* const* d_in, const int* in_sizes, int n_in,
                              void* d_out, int out_size, void* d_ws, size_t ws_size,
                              hipStream_t stream) {
  const float* x     = (const float*)d_in[0];
  const float* w_qkv = (const float*)d_in[1];
  const float* w_out = (const float*)d_in[2];
  const float* gamma = (const float*)d_in[3];
  const float* beta  = (const float*)d_in[4];
  float* out = (float*)d_out;
  char* ws = (char*)d_ws;

  u16* xn  = (u16*)(ws);              //  8 MB  [4096][1024] bf16
  u16* wq  = (u16*)(ws + 8388608);    //  6 MB  [3072][1024] bf16
  u16* wo  = (u16*)(ws + 14680064);   //  2 MB  [1024][1024] bf16
  u16* qkb = (u16*)(ws + 16777216);   // 16 MB  [4096][2048] bf16 (Q|K)
  u16* vt  = (u16*)(ws + 33554432);   //  8 MB  [2][1024][2048] bf16 (V^T)
  u16* ao  = (u16*)(ws + 41943040);   //  8 MB  [4096][1024] bf16 attn out

  ln_kernel<<<4096, 256, 0, stream>>>(x, gamma, beta, xn);
  cvt2_kernel<<<4096, 256, 0, stream>>>(w_qkv, w_out, wq, wo);
  gemm_bt<0><<<32 * 24, 256, 0, stream>>>(xn, wq, 1024, 24, qkb, vt, nullptr, nullptr);
  attn_kernel<<<32 * 32, 256, 0, stream>>>(qkb, vt, ao);
  gemm_bt<1><<<32 * 8, 256, 0, stream>>>(ao, wo, 1024, 8, nullptr, nullptr, x, out);
}